// Round 1
// baseline (7682.786 us; speedup 1.0000x reference)
//
#include <hip/hip_runtime.h>

#define DEVFN __device__ __forceinline__

// ---------------------------------------------------------------------------
// Compile-time exact Clebsch-Gordan tables (e3nn convention, real SH basis).
// Constexpr port of the reference _su2_cg / _real_to_complex / _so3_cg.
// ---------------------------------------------------------------------------
namespace cgc {

constexpr double fact(int n){ double r = 1.0; for(int i = 2; i <= n; ++i) r *= (double)i; return r; }

constexpr double csqrt(double x){
  if(x <= 0.0) return 0.0;
  double g = x < 1.0 ? 1.0 : x;
  for(int i = 0; i < 64; ++i) g = 0.5*(g + x/g);
  return g;
}

constexpr double su2_cg(int j1,int m1,int j2,int m2,int j3,int m3){
  if(m1 + m2 != m3) return 0.0;
  int vmin = -j1 + j2 + m3;
  if(-j1 + m1 > vmin) vmin = -j1 + m1;
  if(0 > vmin) vmin = 0;
  int vmax = j2 + j3 + m1;
  if(j3 - j1 + j2 < vmax) vmax = j3 - j1 + j2;
  if(j3 + m3 < vmax) vmax = j3 + m3;
  double C = (double)(2*j3 + 1)
    * (fact(j3 + j1 - j2)*fact(j3 - j1 + j2)*fact(j1 + j2 - j3)*fact(j3 + m3)*fact(j3 - m3))
    / (fact(j1 + j2 + j3 + 1)*fact(j1 - m1)*fact(j1 + m1)*fact(j2 - m2)*fact(j2 + m2));
  double S = 0.0;
  for(int v = vmin; v <= vmax; ++v){
    double t = (fact(j2 + j3 + m1 - v)*fact(j1 - m1 + v))
      / (fact(v)*fact(j3 - j1 + j2 - v)*fact(j3 + m3 - v)*fact(v + j1 - j2 - m3));
    S += (((v + j2 + m2) & 1) ? -t : t);
  }
  return csqrt(C)*S;
}

struct C2 { double re; double im; };
constexpr C2 cmul(C2 a, C2 b){ return C2{a.re*b.re - a.im*b.im, a.re*b.im + a.im*b.re}; }

struct QM { C2 q[5][5]; };

constexpr QM rtc(int l){
  QM Q{};
  for(int a = 0; a < 5; ++a) for(int b = 0; b < 5; ++b) Q.q[a][b] = C2{0.0,0.0};
  const double inv = 1.0/csqrt(2.0);
  for(int m = -l; m < 0; ++m){
    Q.q[l+m][l-m] = C2{inv, 0.0};     // col l+|m|
    Q.q[l+m][l+m] = C2{0.0, -inv};    // col l-|m|
  }
  Q.q[l][l] = C2{1.0, 0.0};
  for(int m = 1; m <= l; ++m){
    const double sgn = (m & 1) ? -1.0 : 1.0;
    Q.q[l+m][l+m] = C2{sgn*inv, 0.0};
    Q.q[l+m][l-m] = C2{0.0, sgn*inv};
  }
  const C2 ph = (l == 0) ? C2{1.0,0.0} : (l == 1) ? C2{0.0,-1.0} : C2{-1.0,0.0}; // (-i)^l
  for(int a = 0; a < 2*l+1; ++a) for(int b = 0; b < 2*l+1; ++b) Q.q[a][b] = cmul(ph, Q.q[a][b]);
  return Q;
}

struct CG3 { double a[5][5][5]; };

// out[j][l][m] = Re( sum_{i,k,n} Q1[i][j] Q2[k][l] conj(Q3[n][m]) Csu2[i][k][n] )
constexpr CG3 so3(int l1,int l2,int l3){
  const QM Q1 = rtc(l1), Q2 = rtc(l2), Q3 = rtc(l3);
  const int d1 = 2*l1+1, d2 = 2*l2+1, d3 = 2*l3+1;
  CG3 R{};
  for(int a = 0; a < 5; ++a) for(int b = 0; b < 5; ++b) for(int c = 0; c < 5; ++c) R.a[a][b][c] = 0.0;
  for(int i = 0; i < d1; ++i) for(int k = 0; k < d2; ++k){
    const int m1 = i - l1, m2 = k - l2;
    if(m1 + m2 < -l3 || m1 + m2 > l3) continue;
    const int n = m1 + m2 + l3;
    const double c = su2_cg(l1, m1, l2, m2, l3, m1 + m2);
    if(c == 0.0) continue;
    for(int j = 0; j < d1; ++j){
      const C2 q1 = Q1.q[i][j]; if(q1.re == 0.0 && q1.im == 0.0) continue;
      for(int l = 0; l < d2; ++l){
        const C2 q2 = Q2.q[k][l]; if(q2.re == 0.0 && q2.im == 0.0) continue;
        const C2 q12 = cmul(q1, q2);
        for(int m = 0; m < d3; ++m){
          const C2 q3 = Q3.q[n][m]; if(q3.re == 0.0 && q3.im == 0.0) continue;
          const C2 p = cmul(q12, C2{q3.re, -q3.im});
          R.a[j][l][m] += c*p.re;
        }
      }
    }
  }
  return R;
}

constexpr int NCOMB = 15;
// enumeration order must match Python: deg outer, then ni, then no
constexpr int CDEG[NCOMB] = {0,0,0, 1,1,1,1,1,1, 2,2,2,2,2,2};
constexpr int CNI [NCOMB] = {0,1,2, 0,1,1,1,2,2, 0,1,1,2,2,2};
constexpr int CNO [NCOMB] = {0,1,2, 1,0,1,2,1,2, 2,1,2,0,1,2};

struct Tables { float cg[NCOMB][5][5][5]; };
constexpr Tables build(){
  Tables t{};
  for(int ci = 0; ci < NCOMB; ++ci){
    const CG3 r = so3(CDEG[ci], CNI[ci], CNO[ci]);
    for(int i = 0; i < 5; ++i) for(int j = 0; j < 5; ++j) for(int k = 0; k < 5; ++k)
      t.cg[ci][i][j][k] = (float)r.a[i][j][k];
  }
  return t;
}

} // namespace cgc

__device__ constexpr cgc::Tables TAB = cgc::build();

// ---------------------------------------------------------------------------
// Kernel: one thread per edge. Everything in registers, fully unrolled so all
// array indices are compile-time (no scratch) and CG zeros fold away.
// ---------------------------------------------------------------------------

template<int CI>
DEVFN void combo_one(const float (&sh)[9], const float (&x)[72], float (&msg)[72],
                     const float* __restrict__ W){
  constexpr int DEG = cgc::CDEG[CI];
  constexpr int NI  = cgc::CNI[CI];
  constexpr int NO  = cgc::CNO[CI];
  constexpr int DI = 2*DEG + 1, DJ = 2*NI + 1, DK = 2*NO + 1;
  constexpr int SHO = (DEG == 0) ? 0 : ((DEG == 1) ? 1 : 4);
  constexpr int XO  = (NI  == 0) ? 0 : ((NI  == 1) ? 8 : 32);
  constexpr int OO  = (NO  == 0) ? 0 : ((NO  == 1) ? 8 : 32);

  // T[j][k] = sum_i CG[i][j][k] * sh[i]   (CG entries are literals; zeros folded)
  float T[DJ][DK];
#pragma unroll
  for(int j = 0; j < DJ; ++j){
#pragma unroll
    for(int k = 0; k < DK; ++k){
      float acc = 0.0f;
#pragma unroll
      for(int i = 0; i < DI; ++i){
        const float c = TAB.cg[CI][i][j][k];
        if(c != 0.0f) acc += c * sh[SHO + i];
      }
      T[j][k] = acc;
    }
  }

  const float* __restrict__ Wc = W + CI*64;   // uniform address -> scalar loads
#pragma unroll
  for(int c = 0; c < 8; ++c){
    float b[DK];
#pragma unroll
    for(int k = 0; k < DK; ++k){
      float acc = 0.0f;
#pragma unroll
      for(int j = 0; j < DJ; ++j) acc += T[j][k] * x[XO + c*DJ + j];
      b[k] = acc;
    }
#pragma unroll
    for(int o = 0; o < 8; ++o){
      const float w = Wc[c*8 + o];
#pragma unroll
      for(int k = 0; k < DK; ++k) msg[OO + o*DK + k] += b[k]*w;
    }
  }
}

__global__ __launch_bounds__(256)
void cg_layer_kernel(const float* __restrict__ x,
                     const int*   __restrict__ ei,
                     const float* __restrict__ sh0,
                     const float* __restrict__ sh1,
                     const float* __restrict__ sh2,
                     const float* __restrict__ W,
                     float* __restrict__ out,
                     int nEdges){
  const int e = blockIdx.x*blockDim.x + threadIdx.x;
  if(e >= nEdges) return;

  const int src = ei[e];
  const int tgt = ei[nEdges + e];

  float sh[9];
  sh[0] = sh0[e];
  sh[1] = sh1[3*e + 0]; sh[2] = sh1[3*e + 1]; sh[3] = sh1[3*e + 2];
  sh[4] = sh2[5*e + 0]; sh[5] = sh2[5*e + 1]; sh[6] = sh2[5*e + 2];
  sh[7] = sh2[5*e + 3]; sh[8] = sh2[5*e + 4];

  // gather source features (72 f32 = 18 x float4, rows are 288B => 16B aligned)
  float xv[72];
  const float4* __restrict__ xr = reinterpret_cast<const float4*>(x + (size_t)src*72);
#pragma unroll
  for(int t = 0; t < 18; ++t){
    const float4 v = xr[t];
    xv[4*t + 0] = v.x; xv[4*t + 1] = v.y; xv[4*t + 2] = v.z; xv[4*t + 3] = v.w;
  }

  float msg[72];
#pragma unroll
  for(int d = 0; d < 72; ++d) msg[d] = 0.0f;

  combo_one< 0>(sh, xv, msg, W);
  combo_one< 1>(sh, xv, msg, W);
  combo_one< 2>(sh, xv, msg, W);
  combo_one< 3>(sh, xv, msg, W);
  combo_one< 4>(sh, xv, msg, W);
  combo_one< 5>(sh, xv, msg, W);
  combo_one< 6>(sh, xv, msg, W);
  combo_one< 7>(sh, xv, msg, W);
  combo_one< 8>(sh, xv, msg, W);
  combo_one< 9>(sh, xv, msg, W);
  combo_one<10>(sh, xv, msg, W);
  combo_one<11>(sh, xv, msg, W);
  combo_one<12>(sh, xv, msg, W);
  combo_one<13>(sh, xv, msg, W);
  combo_one<14>(sh, xv, msg, W);

  float* op = out + (size_t)tgt*72;
#pragma unroll
  for(int d = 0; d < 72; ++d) unsafeAtomicAdd(op + d, msg[d]);   // hw global_atomic_add_f32
}

// ---------------------------------------------------------------------------

extern "C" void kernel_launch(void* const* d_in, const int* in_sizes, int n_in,
                              void* d_out, int out_size, void* d_ws, size_t ws_size,
                              hipStream_t stream){
  const float* node = (const float*)d_in[0];
  const int*   ei   = (const int*)  d_in[1];
  const float* sh0  = (const float*)d_in[2];
  const float* sh1  = (const float*)d_in[3];
  const float* sh2  = (const float*)d_in[4];
  const float* wts  = (const float*)d_in[5];
  float* out   = (float*)d_out;
  float* inter = (float*)d_ws;     // layer-1 output, [N,72] f32 = 14.4 MB

  const int E = in_sizes[1]/2;
  const int N = in_sizes[0]/72;
  const int blocks = (E + 255)/256;

  hipMemsetAsync(inter, 0, (size_t)N*72*sizeof(float), stream);
  cg_layer_kernel<<<blocks, 256, 0, stream>>>(node, ei, sh0, sh1, sh2,
                                              wts, inter, E);
  hipMemsetAsync(out, 0, (size_t)N*72*sizeof(float), stream);
  cg_layer_kernel<<<blocks, 256, 0, stream>>>(inter, ei, sh0, sh1, sh2,
                                              wts + cgc::NCOMB*64, out, E);
}

// Round 3
// 1298.767 us; speedup vs baseline: 5.9154x; 5.9154x over previous
//
#include <hip/hip_runtime.h>
#include <stdint.h>

#define DEVFN __device__ __forceinline__

// ---------------------------------------------------------------------------
// Compile-time exact Clebsch-Gordan tables (e3nn convention, real SH basis).
// ---------------------------------------------------------------------------
namespace cgc {

constexpr double fact(int n){ double r = 1.0; for(int i = 2; i <= n; ++i) r *= (double)i; return r; }

constexpr double csqrt(double x){
  if(x <= 0.0) return 0.0;
  double g = x < 1.0 ? 1.0 : x;
  for(int i = 0; i < 64; ++i) g = 0.5*(g + x/g);
  return g;
}

constexpr double su2_cg(int j1,int m1,int j2,int m2,int j3,int m3){
  if(m1 + m2 != m3) return 0.0;
  int vmin = -j1 + j2 + m3;
  if(-j1 + m1 > vmin) vmin = -j1 + m1;
  if(0 > vmin) vmin = 0;
  int vmax = j2 + j3 + m1;
  if(j3 - j1 + j2 < vmax) vmax = j3 - j1 + j2;
  if(j3 + m3 < vmax) vmax = j3 + m3;
  double C = (double)(2*j3 + 1)
    * (fact(j3 + j1 - j2)*fact(j3 - j1 + j2)*fact(j1 + j2 - j3)*fact(j3 + m3)*fact(j3 - m3))
    / (fact(j1 + j2 + j3 + 1)*fact(j1 - m1)*fact(j1 + m1)*fact(j2 - m2)*fact(j2 + m2));
  double S = 0.0;
  for(int v = vmin; v <= vmax; ++v){
    double t = (fact(j2 + j3 + m1 - v)*fact(j1 - m1 + v))
      / (fact(v)*fact(j3 - j1 + j2 - v)*fact(j3 + m3 - v)*fact(v + j1 - j2 - m3));
    S += (((v + j2 + m2) & 1) ? -t : t);
  }
  return csqrt(C)*S;
}

struct C2 { double re; double im; };
constexpr C2 cmul(C2 a, C2 b){ return C2{a.re*b.re - a.im*b.im, a.re*b.im + a.im*b.re}; }

struct QM { C2 q[5][5]; };

constexpr QM rtc(int l){
  QM Q{};
  for(int a = 0; a < 5; ++a) for(int b = 0; b < 5; ++b) Q.q[a][b] = C2{0.0,0.0};
  const double inv = 1.0/csqrt(2.0);
  for(int m = -l; m < 0; ++m){
    Q.q[l+m][l-m] = C2{inv, 0.0};
    Q.q[l+m][l+m] = C2{0.0, -inv};
  }
  Q.q[l][l] = C2{1.0, 0.0};
  for(int m = 1; m <= l; ++m){
    const double sgn = (m & 1) ? -1.0 : 1.0;
    Q.q[l+m][l+m] = C2{sgn*inv, 0.0};
    Q.q[l+m][l-m] = C2{0.0, sgn*inv};
  }
  const C2 ph = (l == 0) ? C2{1.0,0.0} : (l == 1) ? C2{0.0,-1.0} : C2{-1.0,0.0}; // (-i)^l
  for(int a = 0; a < 2*l+1; ++a) for(int b = 0; b < 2*l+1; ++b) Q.q[a][b] = cmul(ph, Q.q[a][b]);
  return Q;
}

struct CG3 { double a[5][5][5]; };

constexpr CG3 so3(int l1,int l2,int l3){
  const QM Q1 = rtc(l1), Q2 = rtc(l2), Q3 = rtc(l3);
  const int d1 = 2*l1+1, d2 = 2*l2+1, d3 = 2*l3+1;
  CG3 R{};
  for(int a = 0; a < 5; ++a) for(int b = 0; b < 5; ++b) for(int c = 0; c < 5; ++c) R.a[a][b][c] = 0.0;
  for(int i = 0; i < d1; ++i) for(int k = 0; k < d2; ++k){
    const int m1 = i - l1, m2 = k - l2;
    if(m1 + m2 < -l3 || m1 + m2 > l3) continue;
    const int n = m1 + m2 + l3;
    const double c = su2_cg(l1, m1, l2, m2, l3, m1 + m2);
    if(c == 0.0) continue;
    for(int j = 0; j < d1; ++j){
      const C2 q1 = Q1.q[i][j]; if(q1.re == 0.0 && q1.im == 0.0) continue;
      for(int l = 0; l < d2; ++l){
        const C2 q2 = Q2.q[k][l]; if(q2.re == 0.0 && q2.im == 0.0) continue;
        const C2 q12 = cmul(q1, q2);
        for(int m = 0; m < d3; ++m){
          const C2 q3 = Q3.q[n][m]; if(q3.re == 0.0 && q3.im == 0.0) continue;
          const C2 p = cmul(q12, C2{q3.re, -q3.im});
          R.a[j][l][m] += c*p.re;
        }
      }
    }
  }
  return R;
}

constexpr int NCOMB = 15;
constexpr int CDEG[NCOMB] = {0,0,0, 1,1,1,1,1,1, 2,2,2,2,2,2};
constexpr int CNI [NCOMB] = {0,1,2, 0,1,1,1,2,2, 0,1,1,2,2,2};
constexpr int CNO [NCOMB] = {0,1,2, 1,0,1,2,1,2, 2,1,2,0,1,2};

struct Tables { float cg[NCOMB][5][5][5]; };
constexpr Tables build(){
  Tables t{};
  for(int ci = 0; ci < NCOMB; ++ci){
    const CG3 r = so3(CDEG[ci], CNI[ci], CNO[ci]);
    for(int i = 0; i < 5; ++i) for(int j = 0; j < 5; ++j) for(int k = 0; k < 5; ++k)
      t.cg[ci][i][j][k] = (float)r.a[i][j][k];
  }
  return t;
}

} // namespace cgc

__device__ constexpr cgc::Tables TAB = cgc::build();

// ---------------------------------------------------------------------------
// Per-edge compute (identical math to the round-1 kernel that passed).
// ---------------------------------------------------------------------------

template<int CI>
DEVFN void combo_one(const float (&sh)[9], const float (&x)[72], float (&msg)[72],
                     const float* __restrict__ W){
  constexpr int DEG = cgc::CDEG[CI];
  constexpr int NI  = cgc::CNI[CI];
  constexpr int NO  = cgc::CNO[CI];
  constexpr int DI = 2*DEG + 1, DJ = 2*NI + 1, DK = 2*NO + 1;
  constexpr int SHO = (DEG == 0) ? 0 : ((DEG == 1) ? 1 : 4);
  constexpr int XO  = (NI  == 0) ? 0 : ((NI  == 1) ? 8 : 32);
  constexpr int OO  = (NO  == 0) ? 0 : ((NO  == 1) ? 8 : 32);

  float T[DJ][DK];
#pragma unroll
  for(int j = 0; j < DJ; ++j){
#pragma unroll
    for(int k = 0; k < DK; ++k){
      float acc = 0.0f;
#pragma unroll
      for(int i = 0; i < DI; ++i){
        const float c = TAB.cg[CI][i][j][k];
        if(c != 0.0f) acc += c * sh[SHO + i];
      }
      T[j][k] = acc;
    }
  }

  const float* __restrict__ Wc = W + CI*64;
#pragma unroll
  for(int c = 0; c < 8; ++c){
    float b[DK];
#pragma unroll
    for(int k = 0; k < DK; ++k){
      float acc = 0.0f;
#pragma unroll
      for(int j = 0; j < DJ; ++j) acc += T[j][k] * x[XO + c*DJ + j];
      b[k] = acc;
    }
#pragma unroll
    for(int o = 0; o < 8; ++o){
      const float w = Wc[c*8 + o];
#pragma unroll
      for(int k = 0; k < DK; ++k) msg[OO + o*DK + k] += b[k]*w;
    }
  }
}

DEVFN void edge_accumulate(int eid,
                           const float* __restrict__ x,
                           const int*   __restrict__ ei,
                           const float* __restrict__ sh0,
                           const float* __restrict__ sh1,
                           const float* __restrict__ sh2,
                           const float* __restrict__ W,
                           float (&msg)[72]){
  float sh[9];
  sh[0] = sh0[eid];
  sh[1] = sh1[3*eid + 0]; sh[2] = sh1[3*eid + 1]; sh[3] = sh1[3*eid + 2];
  sh[4] = sh2[5*eid + 0]; sh[5] = sh2[5*eid + 1]; sh[6] = sh2[5*eid + 2];
  sh[7] = sh2[5*eid + 3]; sh[8] = sh2[5*eid + 4];

  const int src = ei[eid];
  float xv[72];
  const float4* __restrict__ xr = reinterpret_cast<const float4*>(x + (size_t)src*72);
#pragma unroll
  for(int t = 0; t < 18; ++t){
    const float4 v = xr[t];
    xv[4*t + 0] = v.x; xv[4*t + 1] = v.y; xv[4*t + 2] = v.z; xv[4*t + 3] = v.w;
  }

  combo_one< 0>(sh, xv, msg, W);
  combo_one< 1>(sh, xv, msg, W);
  combo_one< 2>(sh, xv, msg, W);
  combo_one< 3>(sh, xv, msg, W);
  combo_one< 4>(sh, xv, msg, W);
  combo_one< 5>(sh, xv, msg, W);
  combo_one< 6>(sh, xv, msg, W);
  combo_one< 7>(sh, xv, msg, W);
  combo_one< 8>(sh, xv, msg, W);
  combo_one< 9>(sh, xv, msg, W);
  combo_one<10>(sh, xv, msg, W);
  combo_one<11>(sh, xv, msg, W);
  combo_one<12>(sh, xv, msg, W);
  combo_one<13>(sh, xv, msg, W);
  combo_one<14>(sh, xv, msg, W);
}

// ---------------------------------------------------------------------------
// CSR build — deliberately dumb & verifiable.
// ---------------------------------------------------------------------------

#define NB 32          // target nodes per gather block
#define EIDBITS 27     // bucket word: [31:27]=local node idx, [26:0]=edge id

__global__ __launch_bounds__(256)
void hist_kernel(const int* __restrict__ ei, int* __restrict__ cnt, int E){
  const int e = blockIdx.x*256 + threadIdx.x;
  if(e < E) atomicAdd(&cnt[ei[E + e]], 1);
}

// Per-1024 chunk: exclusive scan (serial by lane 0 in LDS) + chunk total.
__global__ __launch_bounds__(256)
void chunk_scan_kernel(const int* __restrict__ cnt, int* __restrict__ off,
                       int* __restrict__ chunkSum, int N){
  __shared__ int buf[1024];
  const int tid = threadIdx.x;
  const int base = blockIdx.x*1024;
  for(int j = tid; j < 1024; j += 256) buf[j] = (base + j < N) ? cnt[base + j] : 0;
  __syncthreads();
  if(tid == 0){
    int run = 0;
    for(int j = 0; j < 1024; ++j){ const int v = buf[j]; buf[j] = run; run += v; }
    chunkSum[blockIdx.x] = run;
  }
  __syncthreads();
  for(int j = tid; j < 1024; j += 256) if(base + j < N) off[base + j] = buf[j];
}

// Serial exclusive scan of the (~49) chunk sums; also writes off[N] = total.
__global__ __launch_bounds__(64)
void chunk_offsets_kernel(int* __restrict__ chunkSum, int* __restrict__ offN, int C){
  if(threadIdx.x == 0 && blockIdx.x == 0){
    int run = 0;
    for(int c = 0; c < C; ++c){ const int v = chunkSum[c]; chunkSum[c] = run; run += v; }
    offN[0] = run;
  }
}

__global__ __launch_bounds__(256)
void apply_offsets_kernel(int* __restrict__ off, int* __restrict__ cursor,
                          const int* __restrict__ chunkSum, int N){
  const int i = blockIdx.x*256 + threadIdx.x;
  if(i < N){
    const int o = off[i] + chunkSum[i >> 10];
    off[i] = o;
    cursor[i] = o;
  }
}

__global__ __launch_bounds__(256)
void fill_kernel(const int* __restrict__ ei, int* __restrict__ cursor,
                 uint32_t* __restrict__ bucket, int E){
  const int e = blockIdx.x*256 + threadIdx.x;
  if(e >= E) return;
  const int t = ei[E + e];
  const int p = atomicAdd(&cursor[t], 1);
  bucket[p] = (uint32_t)e | ((uint32_t)(t & (NB - 1)) << EIDBITS);
}

// ---------------------------------------------------------------------------
// Gather layer: block owns NB contiguous target nodes. Zero global atomics.
// LDS row index comes from the bucket word's top bits -> structurally in-range.
// ---------------------------------------------------------------------------

__global__ __launch_bounds__(256)
void gather_layer(const float* __restrict__ x,
                  const int*   __restrict__ ei,
                  const float* __restrict__ sh0,
                  const float* __restrict__ sh1,
                  const float* __restrict__ sh2,
                  const int*   __restrict__ off,
                  const uint32_t* __restrict__ bucket,
                  const float* __restrict__ W,
                  float* __restrict__ out,
                  int N){
  __shared__ float acc[NB][73];   // +1 pad: rows spread across banks (73 mod 32 = 9)
  const int tid = threadIdx.x;
  const int n0 = blockIdx.x*NB;
  const int nNodes = min(NB, N - n0);

  float* accf = &acc[0][0];
  for(int idx = tid; idx < NB*73; idx += 256) accf[idx] = 0.0f;
  __syncthreads();

  const int eStart = off[n0];
  const int eEnd   = off[n0 + nNodes];

  for(int p = eStart + tid; p < eEnd; p += 256){
    const uint32_t be = bucket[p];
    const int eid  = (int)(be & ((1u << EIDBITS) - 1u));
    const int lidx = (int)(be >> EIDBITS);

    float msg[72];
#pragma unroll
    for(int d = 0; d < 72; ++d) msg[d] = 0.0f;

    edge_accumulate(eid, x, ei, sh0, sh1, sh2, W, msg);

    float* row = acc[lidx];
#pragma unroll
    for(int d = 0; d < 72; ++d) unsafeAtomicAdd(row + d, msg[d]);  // ds_add_f32
  }
  __syncthreads();

  // coalesced non-atomic write of the block's contiguous output slab
  const int tot = nNodes*72;
  float* obase = out + (size_t)n0*72;
  for(int idx = tid; idx < tot; idx += 256){
    obase[idx] = acc[idx/72][idx%72];
  }
}

// ---------------------------------------------------------------------------

extern "C" void kernel_launch(void* const* d_in, const int* in_sizes, int n_in,
                              void* d_out, int out_size, void* d_ws, size_t ws_size,
                              hipStream_t stream){
  const float* node = (const float*)d_in[0];
  const int*   ei   = (const int*)  d_in[1];
  const float* sh0  = (const float*)d_in[2];
  const float* sh1  = (const float*)d_in[3];
  const float* sh2  = (const float*)d_in[4];
  const float* wts  = (const float*)d_in[5];
  float* out = (float*)d_out;

  const int E = in_sizes[1]/2;
  const int N = in_sizes[0]/72;
  const int C = (N + 1023)/1024;

  // workspace layout (4-byte units)
  int* ws_i = (int*)d_ws;
  int*      cnt      = ws_i;                      // [N]
  int*      off      = ws_i + N;                  // [N+1]
  int*      cursor   = ws_i + 2*N + 1;            // [N]
  int*      chunkSum = ws_i + 3*N + 1;            // [C] (<=64)
  uint32_t* bucket   = (uint32_t*)(ws_i + 3*N + 65); // [E]
  size_t interOff = (size_t)(3*N + 65 + E);
  interOff = (interOff + 3) & ~(size_t)3;         // 16B-align for float4 gathers
  float* inter = (float*)(ws_i + interOff);       // [N*72]

  const int eBlocks = (E + 255)/256;
  const int nBlocks = (N + 255)/256;
  const int gBlocks = (N + NB - 1)/NB;

  // CSR build (targets identical for both layers; rebuilt each launch)
  hipMemsetAsync(cnt, 0, (size_t)N*sizeof(int), stream);
  hist_kernel<<<eBlocks, 256, 0, stream>>>(ei, cnt, E);
  chunk_scan_kernel<<<C, 256, 0, stream>>>(cnt, off, chunkSum, N);
  chunk_offsets_kernel<<<1, 64, 0, stream>>>(chunkSum, off + N, C);
  apply_offsets_kernel<<<nBlocks, 256, 0, stream>>>(off, cursor, chunkSum, N);
  fill_kernel<<<eBlocks, 256, 0, stream>>>(ei, cursor, bucket, E);

  // layer 1: node -> inter
  gather_layer<<<gBlocks, 256, 0, stream>>>(node, ei, sh0, sh1, sh2,
                                            off, bucket, wts, inter, N);
  // layer 2: inter -> out
  gather_layer<<<gBlocks, 256, 0, stream>>>(inter, ei, sh0, sh1, sh2,
                                            off, bucket, wts + cgc::NCOMB*64, out, N);
}